// Round 8
// baseline (31.902 us; speedup 1.0000x reference)
//
#include <hip/hip_runtime.h>

// Problem constants (from reference): B=4, N=512, K=20, C=32
#define Bb 4
#define Nn 512
#define Kk 20
#define Cc 32
#define BNPB 4                 // bn pairs per block (processed sequentially)

typedef float f32x4 __attribute__((ext_vector_type(4)));

// out[b, n, k, c1, c2] = trans[c1,c2] + length[k,c2] + slide[b,n,k,c2]
//                        + (k == (N-1)-n ? E[b,N-1,c1] : 0)
//                        + (n == 0 ? init[c2] : 0)
// slide[b,n,k,c2] = sum_{j=n}^{min(n+k,N)-1} E[b,j,c2]   (k frames, clipped)
//
// R8: 512 blocks x 256 threads (2 blocks/CU, 8 waves/CU), each block walks 4
// consecutive bn -> one 320KB sequential write stream per block. Rationale:
// whole-grid-resident layout (R6) puts ~2048 concurrent 1KB write chunks
// across the full 167MB -> HBM row thrash; fill kernel reaches 87% of peak
// at 10% occupancy with a narrow sweeping front. Stores are dependency-free
// (base staged in LDS, double-buffered: loads for bn+1 issue BEFORE the 20
// stores of bn, prefix+commit after). History: NT stores -13% (R3), store
// batching 0 (R4), low-occupancy with load chain -28% (R5), LDS staging +6%
// (R6), wave-sequential stores 0 (R7).
__global__ __launch_bounds__(256) void semimarkov_scores_kernel(
    const float* __restrict__ trans,   // (C,C)
    const float* __restrict__ emis,    // (B,N,C)
    const float* __restrict__ initv,   // (C,)
    const float* __restrict__ lens,    // (K,C)
    float* __restrict__ out)           // (B, N-1, K, C, C)
{
    __shared__ float base[2][Kk][Cc];  // 5120 B double buffer

    const int tid = threadIdx.x;
    const int c1  = tid >> 3;          // 0..31
    const int q   = tid & 7;           // float4 chunk along c2
    const int bn0 = blockIdx.x * BNPB;
    const int total = Bb * (Nn - 1);   // 2044

    // Invariant per thread: transition row chunk
    const f32x4 t4 = *reinterpret_cast<const f32x4*>(&trans[c1 * Cc + q * 4]);

    // Staging registers (lanes tid<32 only). lens is bn-invariant: load once.
    float lr[Kk], er[Kk], s0 = 0.0f;
    if (tid < Cc) {
        #pragma unroll
        for (int k = 0; k < Kk; ++k) lr[k] = lens[k * Cc + tid];
    }

    // --- stage loads for a given bn into er/s0 (tid<32) ---
    auto stage_load = [&](int bn) {
        if (tid < Cc && bn < total) {
            const int b = bn / (Nn - 1);
            const int n = bn - b * (Nn - 1);
            const float* ebs = &emis[((size_t)b * Nn + n) * Cc + tid];
            #pragma unroll
            for (int k = 0; k < Kk; ++k)
                er[k] = (n + k < Nn) ? ebs[(size_t)k * Cc] : 0.0f;
            s0 = (n == 0) ? initv[tid] : 0.0f;
        }
    };
    // --- prefix + commit to LDS buffer ---
    auto stage_commit = [&](int buf) {
        if (tid < Cc) {
            float s = s0;
            #pragma unroll
            for (int k = 0; k < Kk; ++k) {
                base[buf][k][tid] = lr[k] + s;   // slide excludes frame n+k
                s += er[k];
            }
        }
    };

    stage_load(bn0);
    stage_commit(0);
    __syncthreads();

    for (int j = 0; j < BNPB; ++j) {
        const int bn = bn0 + j;
        if (bn >= total) break;        // uniform per block
        const int b = bn / (Nn - 1);
        const int n = bn - b * (Nn - 1);

        // issue next bn's staging loads before the store burst (latency hides)
        stage_load(bn + 1);

        const int   k_eos  = (Nn - 1) - n;   // >= 1 always
        const float e_last = (k_eos < Kk)
            ? emis[((size_t)b * Nn + (Nn - 1)) * Cc + c1]
            : 0.0f;

        float* ob = &out[(size_t)bn * (size_t)(Kk * Cc * Cc)
                         + (size_t)(c1 * Cc + q * 4)];
        const int buf = j & 1;
        #pragma unroll
        for (int k = 0; k < Kk; ++k) {
            f32x4 v = t4 + *reinterpret_cast<const f32x4*>(&base[buf][k][q * 4]);
            if (k == k_eos) v += (f32x4)(e_last);
            *reinterpret_cast<f32x4*>(&ob[(size_t)k * (Cc * Cc)]) = v;
        }

        stage_commit((j + 1) & 1);     // other buffer: safe vs. current readers
        __syncthreads();               // next iter reads committed buffer
    }
}

extern "C" void kernel_launch(void* const* d_in, const int* in_sizes, int n_in,
                              void* d_out, int out_size, void* d_ws, size_t ws_size,
                              hipStream_t stream) {
    const float* trans = (const float*)d_in[0];   // (C,C)
    const float* emis  = (const float*)d_in[1];   // (B,N,C)
    const float* initv = (const float*)d_in[2];   // (C,)
    const float* lens  = (const float*)d_in[3];   // (K,C)
    float* out = (float*)d_out;                   // (B, N-1, K, C, C)

    const int total = Bb * (Nn - 1);              // 2044
    const int grid  = (total + BNPB - 1) / BNPB;  // 511 -> pad to 512
    semimarkov_scores_kernel<<<(grid + 1) & ~1, 256, 0, stream>>>(trans, emis, initv, lens, out);
}

// Round 9
// 30.919 us; speedup vs baseline: 1.0318x; 1.0318x over previous
//
#include <hip/hip_runtime.h>

// Problem constants (from reference): B=4, N=512, K=20, C=32
#define Bb 4
#define Nn 512
#define Kk 20
#define Cc 32

typedef float f32x4 __attribute__((ext_vector_type(4)));

// out[b, n, k, c1, c2] = trans[c1,c2] + length[k,c2] + slide[b,n,k,c2]
//                        + (k == (N-1)-n ? E[b,N-1,c1] : 0)
//                        + (n == 0 ? init[c2] : 0)
// slide[b,n,k,c2] = sum_{j=n}^{min(n+k,N)-1} E[b,j,c2]   (k frames, clipped)
//
// R9 = revert to R6 (best: 30.9us = 5.4 TB/s effective write BW).
// One block per (b,n), 2044 blocks x 256 threads (full 32 waves/CU).
// Wave 0 lanes 0..31 stage base[k][c2] = lens + slide (+init) into LDS
// (independent global loads, register prefix sum), barrier, then every
// thread emits 20 dependency-free float4 stores (base via conflict-free
// broadcast ds_read_b128).
//
// Experiment history (dur_us):
//   R1 direct per-thread running sum            32.7
//   R3 + nontemporal stores                     37.0  (NT steady-state slower)
//   R4 + 5-deep store batching                  32.9  (issue order irrelevant)
//   R5 4bn/block, 2 blk/CU, load chain in path  41.8  (latency-bound)
//   R6 LDS-staged base, full grid               30.9  <- best
//   R7 k-across-waves sequential wave streams   31.3  (layout irrelevant)
//   R8 4bn/block dbuf staged, 2 blk/CU          31.9  (stream count irrelevant)
// Residual vs fill-kernel rate (6.7 TB/s) is consistent with a ~5-6us fixed
// per-dispatch cost (launch + ramp + end-of-kernel dirty-L2 writeback) that
// a 25us transfer cannot amortize: effective write roofline for this size.
__global__ __launch_bounds__(256) void semimarkov_scores_kernel(
    const float* __restrict__ trans,   // (C,C)
    const float* __restrict__ emis,    // (B,N,C)
    const float* __restrict__ initv,   // (C,)
    const float* __restrict__ lens,    // (K,C)
    float* __restrict__ out)           // (B, N-1, K, C, C)
{
    __shared__ float base[Kk][Cc];     // 2560 B

    const int tid = threadIdx.x;
    const int c1  = tid >> 3;          // 0..31
    const int q   = tid & 7;           // float4 index along c2 (c2 = 4q..4q+3)
    const int bn  = blockIdx.x;        // b*(N-1) + n
    const int b   = bn / (Nn - 1);
    const int n   = bn - b * (Nn - 1);

    // Per-thread invariants (issued before the barrier so latency overlaps)
    const f32x4 t4 = *reinterpret_cast<const f32x4*>(&trans[c1 * Cc + q * 4]);
    const int   k_eos  = (Nn - 1) - n;                 // >= 1 always
    const float e_last = (k_eos < Kk)
        ? emis[((size_t)b * Nn + (Nn - 1)) * Cc + c1]
        : 0.0f;

    // Stage base[k][c2] with 32 lanes of wave 0.
    if (tid < Cc) {
        const int c2 = tid;
        float l[Kk], e[Kk];
        const float* ebs = &emis[((size_t)b * Nn + n) * Cc + c2];
        #pragma unroll
        for (int k = 0; k < Kk; ++k) {
            l[k] = lens[k * Cc + c2];                  // independent loads
            e[k] = (n + k < Nn) ? ebs[(size_t)k * Cc] : 0.0f;
        }
        float s = (n == 0) ? initv[c2] : 0.0f;
        #pragma unroll
        for (int k = 0; k < Kk; ++k) {
            base[k][c2] = l[k] + s;                    // slide[k] excludes frame n+k
            s += e[k];
        }
    }
    __syncthreads();

    float* ob = &out[(size_t)bn * (size_t)(Kk * Cc * Cc)
                     + (size_t)(c1 * Cc + q * 4)];
    #pragma unroll
    for (int k = 0; k < Kk; ++k) {
        f32x4 v = t4 + *reinterpret_cast<const f32x4*>(&base[k][q * 4]);
        if (k == k_eos) {
            v += (f32x4)(e_last);
        }
        *reinterpret_cast<f32x4*>(&ob[(size_t)k * (Cc * Cc)]) = v;
    }
}

extern "C" void kernel_launch(void* const* d_in, const int* in_sizes, int n_in,
                              void* d_out, int out_size, void* d_ws, size_t ws_size,
                              hipStream_t stream) {
    const float* trans = (const float*)d_in[0];   // (C,C)
    const float* emis  = (const float*)d_in[1];   // (B,N,C)
    const float* initv = (const float*)d_in[2];   // (C,)
    const float* lens  = (const float*)d_in[3];   // (K,C)
    float* out = (float*)d_out;                   // (B, N-1, K, C, C)

    const int grid = Bb * (Nn - 1);               // 2044 blocks
    semimarkov_scores_kernel<<<grid, 256, 0, stream>>>(trans, emis, initv, lens, out);
}